// Round 9
// baseline (163.687 us; speedup 1.0000x reference)
//
#include <hip/hip_runtime.h>
#include <hip/hip_bf16.h>

#define Bv 32
#define Dv 512
#define Kv 64
#define Nv 1024
#define EPSv 1e-12f

typedef __attribute__((ext_vector_type(8))) short bf16x8;
typedef __attribute__((ext_vector_type(4))) float f32x4;

// fp32 -> bf16 (RNE), bit-level
__device__ __forceinline__ unsigned short f2b(float f) {
  union { float f; unsigned u; } v; v.f = f;
  unsigned r = v.u + 0x7fffu + ((v.u >> 16) & 1u);
  return (unsigned short)(r >> 16);
}
__device__ __forceinline__ unsigned pack2(float a, float b) {
  return (unsigned)f2b(a) | ((unsigned)f2b(b) << 16);
}

// async global->LDS DMA, 16 B per lane (global_load_lds_dwordx4)
__device__ __forceinline__ void gload_lds16(const float* g, float* l) {
  __builtin_amdgcn_global_load_lds(
      (const __attribute__((address_space(1))) unsigned*)g,
      (__attribute__((address_space(3))) unsigned*)l, 16, 0, 0);
}

// ---------------------------------------------------------------------------
// Kernel W: convert conv_w (K x D fp32) -> bf16. 32 blocks x 256 thr.
// ---------------------------------------------------------------------------
__global__ __launch_bounds__(256) void wconv(const float* __restrict__ w,
                                             unsigned short* __restrict__ wbf) {
  int i = (blockIdx.x * 256 + threadIdx.x) * 4;
  float4 v = *(const float4*)&w[i];
  uint2 o = make_uint2(pack2(v.x, v.y), pack2(v.z, v.w));
  *(uint2*)&wbf[i] = o;
}

// ---------------------------------------------------------------------------
// Kernel 1 (fused): per (b, 32-n tile):
//  - preload all 16 wbf A-frags into registers (L2-hot)
//  - async-DMA x fp32 [512d x 32n] -> LDS (8x global_load_lds 16B/lane per
//    wave; zero VGPR cost -> full MLP independent of register allocator)
//  - xbf bf16 write via plain float4 re-reads (MSHR-merged with DMAs)
//  - scores GEMM 64k x 32n: B-frags from LDS fp32 + f2b, MFMA w/ preloaded A
//  - softmax over k via shuffle + small LDS reductions (union'd with x tile)
//  - write assign bf16 + asum atomics
// Grid (N/32, B) = (32, 32) = 1024 blocks, 512 threads (8 waves).
// LDS = 64 KB exactly -> 2 blocks/CU, 16 waves/CU; VGPR cap 128 via (512,4).
// ---------------------------------------------------------------------------
__global__ __launch_bounds__(512, 4) void fused_scores(
    const float* __restrict__ x, const unsigned short* __restrict__ wbf,
    unsigned short* __restrict__ xbf, unsigned short* __restrict__ assign,
    float* __restrict__ asum) {
  __shared__ union SMem {
    float xs[512 * 32];                 // fp32 x-tile [d][n], pitch 32 (64 KB)
    struct { float redmax[4][32]; float redsum[4][32]; } r;  // dead-xs reuse
  } sm;

  const int t = threadIdx.x;   // 0..511
  const int b = blockIdx.y;
  const int n0 = blockIdx.x * 32;
  const int wv = t >> 6;
  const int lane = t & 63;
  const int q = lane >> 4;
  const int m = lane & 15;
  const int k16 = wv & 3;       // k-tile
  const int nsub = wv >> 2;     // n-half: cols [nsub*16, +16)

  const float* xb = x + (size_t)b * Dv * Nv + n0;

  // ---- A-frag preload: 16 frags x 16 B (held in VGPRs through the GEMM) ----
  const unsigned short* wp = wbf + (size_t)(k16 * 16 + m) * Dv + q * 8;
  bf16x8 af[16];
#pragma unroll
  for (int i = 0; i < 16; i++) af[i] = *(const bf16x8*)(wp + i * 32);

  // ---- async DMA staging: wave wv covers d-rows [wv*64, wv*64+64) ----
  {
    const int row8 = lane >> 3;         // 0..7
    const int nq = (lane & 7) * 4;      // n-quad
#pragma unroll
    for (int r = 0; r < 8; r++) {
      int d = wv * 64 + r * 8 + row8;
      gload_lds16(&xb[(size_t)d * Nv + nq], &sm.xs[(wv * 64 + r * 8) * 32]);
    }
  }

  // ---- xbf write via re-read (lines already in flight -> L2 hit/merge) ----
  {
    const int row = t >> 3;             // 0..63
    const int nq = (t & 7) * 4;
    unsigned short* xo = xbf + (size_t)b * Dv * Nv + n0;
#pragma unroll
    for (int r = 0; r < 8; r++) {
      int d = r * 64 + row;
      float4 v = *(const float4*)&xb[(size_t)d * Nv + nq];
      *(uint2*)&xo[(size_t)d * Nv + nq] =
          make_uint2(pack2(v.x, v.y), pack2(v.z, v.w));
    }
  }
  __syncthreads();   // drains DMA vmcnt

  // ---- scores GEMM: B-frag from LDS fp32, A from registers ----
  const int col = nsub * 16 + m;
  const float* lp = &sm.xs[(q * 8) * 32 + col];
  f32x4 acc = {0.f, 0.f, 0.f, 0.f};
#pragma unroll
  for (int i = 0; i < 16; i++) {
    bf16x8 bfv;
#pragma unroll
    for (int j = 0; j < 8; j++)
      bfv[j] = (short)f2b(lp[i * 1024 + j * 32]);
    acc = __builtin_amdgcn_mfma_f32_16x16x32_bf16(af[i], bfv, acc, 0, 0, 0);
  }
  __syncthreads();   // all xs reads done before red arrays overwrite the union

  // ---- softmax over k (64); lane (q,m): rows k16*16+q*4+r, col n0+col ----
  float mx = fmaxf(fmaxf(acc[0], acc[1]), fmaxf(acc[2], acc[3]));
  mx = fmaxf(mx, __shfl_xor(mx, 16));
  mx = fmaxf(mx, __shfl_xor(mx, 32));
  if (q == 0) sm.r.redmax[k16][col] = mx;
  __syncthreads();
  float mc = fmaxf(fmaxf(sm.r.redmax[0][col], sm.r.redmax[1][col]),
                   fmaxf(sm.r.redmax[2][col], sm.r.redmax[3][col]));
  float e[4];
  float s = 0.f;
#pragma unroll
  for (int r = 0; r < 4; r++) { e[r] = __expf(acc[r] - mc); s += e[r]; }
  s += __shfl_xor(s, 16);
  s += __shfl_xor(s, 32);
  if (q == 0) sm.r.redsum[k16][col] = s;
  __syncthreads();
  float sc = 1.0f / (sm.r.redsum[0][col] + sm.r.redsum[1][col] +
                     sm.r.redsum[2][col] + sm.r.redsum[3][col]);

  // ---- assign write + asum atomics ----
  unsigned short* ab = assign + ((size_t)b * Kv + k16 * 16 + q * 4) * Nv + n0 + nsub * 16;
#pragma unroll
  for (int r = 0; r < 4; r++) {
    float v = e[r] * sc;
    ab[(size_t)r * Nv + m] = f2b(v);
    v += __shfl_xor(v, 1); v += __shfl_xor(v, 2);
    v += __shfl_xor(v, 4); v += __shfl_xor(v, 8);
    if (m == 0) atomicAdd(&asum[b * Kv + k16 * 16 + q * 4 + r], v);
  }
}

// ---------------------------------------------------------------------------
// Kernel 2: vlad[b,d,k] = sum_n xbf*assign - centers*asum via bf16 MFMA.
// One block owns ALL 64 k for a 16-d stripe (x-tile read once). Pure
// load->MFMA loop, register-pipelined depth 8 (16 loads in flight).
// __launch_bounds__(512,4): VGPR cap 128, 2 blocks/CU, 16 waves/CU.
// Grid (D/16, B) = (32, 32), 512 threads: wave = (ksub 0..3, nh 0..1).
// Fuses colsq via atomics.
// ---------------------------------------------------------------------------
__global__ __launch_bounds__(512, 4) void vlad_mfma(
    const unsigned short* __restrict__ xbf, const unsigned short* __restrict__ assign,
    const float* __restrict__ centers, const float* __restrict__ asum,
    float* __restrict__ vlad, float* __restrict__ colsq) {
  __shared__ float sred[4][64][4];   // [ksub][lane][r] from nh==1 waves

  const int t = threadIdx.x;
  const int b = blockIdx.y;
  const int d0 = blockIdx.x * 16;
  const int wv = t >> 6;
  const int ksub = wv & 3;
  const int nh = wv >> 2;            // n-half
  const int lane = t & 63;
  const int q = lane >> 4;
  const int m = lane & 15;
  const int k16 = ksub * 16;

  const unsigned short* xp = xbf + ((size_t)b * Dv + d0 + m) * Nv + nh * 512 + q * 8;
  const unsigned short* ap = assign + ((size_t)b * Kv + k16 + m) * Nv + nh * 512 + q * 8;

  f32x4 acc = {0.f, 0.f, 0.f, 0.f};
  bf16x8 xv[8], av[8];
#pragma unroll
  for (int i = 0; i < 8; i++) {
    xv[i] = *(const bf16x8*)(xp + i * 32);
    av[i] = *(const bf16x8*)(ap + i * 32);
  }
#pragma unroll
  for (int i = 0; i < 8; i++) {
    acc = __builtin_amdgcn_mfma_f32_16x16x32_bf16(xv[i], av[i], acc, 0, 0, 0);
    xv[i] = *(const bf16x8*)(xp + 256 + i * 32);
    av[i] = *(const bf16x8*)(ap + 256 + i * 32);
  }
#pragma unroll
  for (int i = 0; i < 8; i++)
    acc = __builtin_amdgcn_mfma_f32_16x16x32_bf16(xv[i], av[i], acc, 0, 0, 0);

  if (nh == 1) {
#pragma unroll
    for (int r = 0; r < 4; r++) sred[ksub][lane][r] = acc[r];
  }
  __syncthreads();
  if (nh == 0) {
    const int k = k16 + m;
    const float as = asum[b * Kv + k];
    float ss = 0.f;
#pragma unroll
    for (int r = 0; r < 4; r++) {
      float v = acc[r] + sred[ksub][lane][r];
      int d = d0 + q * 4 + r;
      float val = v - centers[d * Kv + k] * as;
      vlad[((size_t)b * Dv + d) * Kv + k] = val;
      ss = fmaf(val, val, ss);
    }
    ss += __shfl_xor(ss, 16);
    ss += __shfl_xor(ss, 32);
    if (q == 0) atomicAdd(&colsq[b * Kv + k], ss);
  }
}

// ---------------------------------------------------------------------------
// Kernel D: out = vlad * colscale[b,k] * bscale[b]; scales from colsq
// in-block. Grid 4096 x 256.
// ---------------------------------------------------------------------------
__global__ __launch_bounds__(256) void scale_kernel(
    const float* __restrict__ vlad, const float* __restrict__ colsq,
    float* __restrict__ out) {
  const int t = threadIdx.x;
  const size_t i = (size_t)blockIdx.x * 256 + t;
  const int b = (int)(i >> 15);  // D*K = 32768 per b
  __shared__ float scs[64];
  __shared__ float bsh;
  if (t < 64) {
    float tot = colsq[b * Kv + t];
    float sc = 1.0f / fmaxf(sqrtf(tot), EPSv);
    scs[t] = sc;
    float contrib = tot * sc * sc;
#pragma unroll
    for (int off = 32; off > 0; off >>= 1) contrib += __shfl_down(contrib, off);
    if (t == 0) bsh = 1.0f / fmaxf(sqrtf(contrib), EPSv);
  }
  __syncthreads();
  out[i] = vlad[i] * scs[i & 63] * bsh;
}

extern "C" void kernel_launch(void* const* d_in, const int* in_sizes, int n_in,
                              void* d_out, int out_size, void* d_ws, size_t ws_size,
                              hipStream_t stream) {
  const float* x = (const float*)d_in[0];        // [B, D, N]
  const float* w = (const float*)d_in[1];        // [K, D]
  const float* centers = (const float*)d_in[2];  // [D, K]
  float* out = (float*)d_out;                    // [B, D*K]

  char* ws = (char*)d_ws;
  unsigned short* assign = (unsigned short*)ws;               // [B][K][N] bf16, 4 MB
  float* vlad = (float*)(ws + 4194304);                       // [B][D][K] fp32, 4 MB
  unsigned short* xbf = (unsigned short*)(ws + 8388608);      // [B][D][N] bf16, 32 MB
  unsigned short* wbf = (unsigned short*)(ws + 41943040);     // [K][D] bf16, 64 KB
  float* asum = (float*)(ws + 42008576);                      // B*K
  float* colsq = asum + Bv * Kv;                              // B*K (contiguous)

  hipMemsetAsync(asum, 0, (size_t)2 * Bv * Kv * sizeof(float), stream);

  wconv<<<32, 256, 0, stream>>>(w, wbf);
  fused_scores<<<dim3(Nv / 32, Bv), 512, 0, stream>>>(x, wbf, xbf, assign, asum);
  vlad_mfma<<<dim3(Dv / 16, Bv), 512, 0, stream>>>(xbf, assign, centers, asum, vlad, colsq);
  scale_kernel<<<(Bv * Dv * Kv) / 256, 256, 0, stream>>>(vlad, colsq, out);
}

// Round 10
// 147.386 us; speedup vs baseline: 1.1106x; 1.1106x over previous
//
#include <hip/hip_runtime.h>
#include <hip/hip_bf16.h>

#define Bv 32
#define Dv 512
#define Kv 64
#define Nv 1024
#define EPSv 1e-12f

typedef __attribute__((ext_vector_type(8))) short bf16x8;
typedef __attribute__((ext_vector_type(4))) float f32x4;

// fp32 -> bf16 (RNE), bit-level
__device__ __forceinline__ unsigned short f2b(float f) {
  union { float f; unsigned u; } v; v.f = f;
  unsigned r = v.u + 0x7fffu + ((v.u >> 16) & 1u);
  return (unsigned short)(r >> 16);
}
__device__ __forceinline__ unsigned pack2(float a, float b) {
  return (unsigned)f2b(a) | ((unsigned)f2b(b) << 16);
}

// ---------------------------------------------------------------------------
// Kernel W: convert conv_w (K x D fp32) -> bf16. 32 blocks x 256 thr.
// ---------------------------------------------------------------------------
__global__ __launch_bounds__(256) void wconv(const float* __restrict__ w,
                                             unsigned short* __restrict__ wbf) {
  int i = (blockIdx.x * 256 + threadIdx.x) * 4;
  float4 v = *(const float4*)&w[i];
  uint2 o = make_uint2(pack2(v.x, v.y), pack2(v.z, v.w));
  *(uint2*)&wbf[i] = o;
}

// ---------------------------------------------------------------------------
// Kernel 1 (fused T+A) — R5 configuration (best measured, <41 us):
// per (b, 64-n tile):
//  - stage x fp32 [512d x 64n] -> LDS xT[n][d] bf16 (pitch 520) + xbf global
//  - scores GEMM 64k x 64n via MFMA (A from wbf L2, B ds_read_b128)
//  - softmax over k via shuffle + small LDS cross-wave reductions
//  - write assign bf16 + asum atomics (pre-quantization values)
// Grid (N/64, B) = (16, 32) = 512 blocks, 512 threads (8 waves).
// LDS ~68.6 KB -> 2 blocks/CU, 16 waves/CU.
// ---------------------------------------------------------------------------
__global__ __launch_bounds__(512) void fused_scores(
    const float* __restrict__ x, const unsigned short* __restrict__ wbf,
    unsigned short* __restrict__ xbf, unsigned short* __restrict__ assign,
    float* __restrict__ asum) {
  __shared__ unsigned short xT[64 * 520];   // [n][d], pitch 520 shorts (1040B)
  __shared__ float redmax[4][64];
  __shared__ float redsum[4][64];

  const int t = threadIdx.x;   // 0..511
  const int b = blockIdx.y;
  const int n0 = blockIdx.x * 64;

  // ---------------- staging (also writes xbf) ----------------
  {
    const int lo = t & 15;     // n-quad
    const int hi = t >> 4;     // 0..31 (d-pair subindex)
    const float* xb = x + (size_t)b * Dv * Nv + n0;
    unsigned short* xo = xbf + (size_t)b * Dv * Nv + n0;
#pragma unroll
    for (int r = 0; r < 8; r++) {
      int d = (hi + 32 * r) * 2;        // even d row; covers 0..510
      int n4 = lo * 4;
      float4 v0 = *(const float4*)&xb[(size_t)d * Nv + n4];
      float4 v1 = *(const float4*)&xb[(size_t)(d + 1) * Nv + n4];
      *(uint2*)&xo[(size_t)d * Nv + n4] =
          make_uint2(pack2(v0.x, v0.y), pack2(v0.z, v0.w));
      *(uint2*)&xo[(size_t)(d + 1) * Nv + n4] =
          make_uint2(pack2(v1.x, v1.y), pack2(v1.z, v1.w));
      // LDS xT: dword at [n][d] = (x[d][n], x[d+1][n]); d even -> aligned
      *(unsigned*)&xT[(n4 + 0) * 520 + d] = pack2(v0.x, v1.x);
      *(unsigned*)&xT[(n4 + 1) * 520 + d] = pack2(v0.y, v1.y);
      *(unsigned*)&xT[(n4 + 2) * 520 + d] = pack2(v0.z, v1.z);
      *(unsigned*)&xT[(n4 + 3) * 520 + d] = pack2(v0.w, v1.w);
    }
  }
  __syncthreads();

  // ---------------- scores GEMM ----------------
  const int wv = t >> 6;        // 0..7
  const int lane = t & 63;
  const int q = lane >> 4;
  const int m = lane & 15;
  const int k16 = wv & 3;       // k-tile
  const int nsub = wv >> 2;     // n-half: cols [nsub*32, +32)

  f32x4 acc0 = {0.f, 0.f, 0.f, 0.f};
  f32x4 acc1 = {0.f, 0.f, 0.f, 0.f};

  const unsigned short* wp = wbf + (size_t)(k16 * 16 + m) * Dv + q * 8;
  const unsigned short* l0 = &xT[(nsub * 32 + m) * 520 + q * 8];
  const unsigned short* l1 = l0 + 16 * 520;

#pragma unroll
  for (int d0 = 0; d0 < Dv; d0 += 32) {
    bf16x8 af = *(const bf16x8*)(wp + d0);
    bf16x8 bf0 = *(const bf16x8*)(l0 + d0);
    bf16x8 bf1 = *(const bf16x8*)(l1 + d0);
    acc0 = __builtin_amdgcn_mfma_f32_16x16x32_bf16(af, bf0, acc0, 0, 0, 0);
    acc1 = __builtin_amdgcn_mfma_f32_16x16x32_bf16(af, bf1, acc1, 0, 0, 0);
  }

  // ---------------- softmax over k (64) ----------------
  // lane (q,m) holds rows k16*16 + q*4 + r, cols n0 + nsub*32 + {m, 16+m}
  float m0 = fmaxf(fmaxf(acc0[0], acc0[1]), fmaxf(acc0[2], acc0[3]));
  float m1 = fmaxf(fmaxf(acc1[0], acc1[1]), fmaxf(acc1[2], acc1[3]));
  m0 = fmaxf(m0, __shfl_xor(m0, 16)); m0 = fmaxf(m0, __shfl_xor(m0, 32));
  m1 = fmaxf(m1, __shfl_xor(m1, 16)); m1 = fmaxf(m1, __shfl_xor(m1, 32));
  if (q == 0) {
    redmax[k16][nsub * 32 + m] = m0;
    redmax[k16][nsub * 32 + 16 + m] = m1;
  }
  __syncthreads();
  const int c0 = nsub * 32 + m, c1 = c0 + 16;
  float mc0 = fmaxf(fmaxf(redmax[0][c0], redmax[1][c0]), fmaxf(redmax[2][c0], redmax[3][c0]));
  float mc1 = fmaxf(fmaxf(redmax[0][c1], redmax[1][c1]), fmaxf(redmax[2][c1], redmax[3][c1]));

  float e0[4], e1[4];
  float s0 = 0.f, s1 = 0.f;
#pragma unroll
  for (int r = 0; r < 4; r++) {
    e0[r] = __expf(acc0[r] - mc0); s0 += e0[r];
    e1[r] = __expf(acc1[r] - mc1); s1 += e1[r];
  }
  s0 += __shfl_xor(s0, 16); s0 += __shfl_xor(s0, 32);
  s1 += __shfl_xor(s1, 16); s1 += __shfl_xor(s1, 32);
  if (q == 0) {
    redsum[k16][c0] = s0;
    redsum[k16][c1] = s1;
  }
  __syncthreads();
  float sc0 = 1.0f / (redsum[0][c0] + redsum[1][c0] + redsum[2][c0] + redsum[3][c0]);
  float sc1 = 1.0f / (redsum[0][c1] + redsum[1][c1] + redsum[2][c1] + redsum[3][c1]);

  // ---------------- assign write + asum ----------------
  unsigned short* ab = assign + ((size_t)b * Kv + k16 * 16 + q * 4) * Nv + n0 + nsub * 32;
#pragma unroll
  for (int r = 0; r < 4; r++) {
    float v0 = e0[r] * sc0;
    float v1 = e1[r] * sc1;
    ab[(size_t)r * Nv + m] = f2b(v0);
    ab[(size_t)r * Nv + 16 + m] = f2b(v1);
    float p = v0 + v1;
    p += __shfl_xor(p, 1); p += __shfl_xor(p, 2);
    p += __shfl_xor(p, 4); p += __shfl_xor(p, 8);
    if (m == 0) atomicAdd(&asum[b * Kv + k16 * 16 + q * 4 + r], p);
  }
}

// ---------------------------------------------------------------------------
// Kernel 2: vlad[b,d,k] = sum_n xbf*assign - centers*asum via bf16 MFMA.
// One block owns ALL 64 k for a 16-d stripe -> x-tile read exactly ONCE
// (halves xbf traffic vs R5's k-split blocks). Pure load->MFMA loop,
// register-pipelined depth 8. __launch_bounds__(512,4): VGPR cap 128.
// Grid (D/16, B) = (32, 32), 512 threads: wave = (ksub 0..3, nh 0..1).
// Fuses colsq via atomics.
// ---------------------------------------------------------------------------
__global__ __launch_bounds__(512, 4) void vlad_mfma(
    const unsigned short* __restrict__ xbf, const unsigned short* __restrict__ assign,
    const float* __restrict__ centers, const float* __restrict__ asum,
    float* __restrict__ vlad, float* __restrict__ colsq) {
  __shared__ float sred[4][64][4];   // [ksub][lane][r] from nh==1 waves

  const int t = threadIdx.x;
  const int b = blockIdx.y;
  const int d0 = blockIdx.x * 16;
  const int wv = t >> 6;
  const int ksub = wv & 3;
  const int nh = wv >> 2;            // n-half
  const int lane = t & 63;
  const int q = lane >> 4;
  const int m = lane & 15;
  const int k16 = ksub * 16;

  const unsigned short* xp = xbf + ((size_t)b * Dv + d0 + m) * Nv + nh * 512 + q * 8;
  const unsigned short* ap = assign + ((size_t)b * Kv + k16 + m) * Nv + nh * 512 + q * 8;

  f32x4 acc = {0.f, 0.f, 0.f, 0.f};
  bf16x8 xv[8], av[8];
#pragma unroll
  for (int i = 0; i < 8; i++) {
    xv[i] = *(const bf16x8*)(xp + i * 32);
    av[i] = *(const bf16x8*)(ap + i * 32);
  }
#pragma unroll
  for (int i = 0; i < 8; i++) {
    acc = __builtin_amdgcn_mfma_f32_16x16x32_bf16(xv[i], av[i], acc, 0, 0, 0);
    xv[i] = *(const bf16x8*)(xp + 256 + i * 32);
    av[i] = *(const bf16x8*)(ap + 256 + i * 32);
  }
#pragma unroll
  for (int i = 0; i < 8; i++)
    acc = __builtin_amdgcn_mfma_f32_16x16x32_bf16(xv[i], av[i], acc, 0, 0, 0);

  if (nh == 1) {
#pragma unroll
    for (int r = 0; r < 4; r++) sred[ksub][lane][r] = acc[r];
  }
  __syncthreads();
  if (nh == 0) {
    const int k = k16 + m;
    const float as = asum[b * Kv + k];
    float ss = 0.f;
#pragma unroll
    for (int r = 0; r < 4; r++) {
      float v = acc[r] + sred[ksub][lane][r];
      int d = d0 + q * 4 + r;
      float val = v - centers[d * Kv + k] * as;
      vlad[((size_t)b * Dv + d) * Kv + k] = val;
      ss = fmaf(val, val, ss);
    }
    ss += __shfl_xor(ss, 16);
    ss += __shfl_xor(ss, 32);
    if (q == 0) atomicAdd(&colsq[b * Kv + k], ss);
  }
}

// ---------------------------------------------------------------------------
// Kernel D: out = vlad * colscale[b,k] * bscale[b]; scales from colsq
// in-block. Grid 4096 x 256.
// ---------------------------------------------------------------------------
__global__ __launch_bounds__(256) void scale_kernel(
    const float* __restrict__ vlad, const float* __restrict__ colsq,
    float* __restrict__ out) {
  const int t = threadIdx.x;
  const size_t i = (size_t)blockIdx.x * 256 + t;
  const int b = (int)(i >> 15);  // D*K = 32768 per b
  __shared__ float scs[64];
  __shared__ float bsh;
  if (t < 64) {
    float tot = colsq[b * Kv + t];
    float sc = 1.0f / fmaxf(sqrtf(tot), EPSv);
    scs[t] = sc;
    float contrib = tot * sc * sc;
#pragma unroll
    for (int off = 32; off > 0; off >>= 1) contrib += __shfl_down(contrib, off);
    if (t == 0) bsh = 1.0f / fmaxf(sqrtf(contrib), EPSv);
  }
  __syncthreads();
  out[i] = vlad[i] * scs[i & 63] * bsh;
}

extern "C" void kernel_launch(void* const* d_in, const int* in_sizes, int n_in,
                              void* d_out, int out_size, void* d_ws, size_t ws_size,
                              hipStream_t stream) {
  const float* x = (const float*)d_in[0];        // [B, D, N]
  const float* w = (const float*)d_in[1];        // [K, D]
  const float* centers = (const float*)d_in[2];  // [D, K]
  float* out = (float*)d_out;                    // [B, D*K]

  char* ws = (char*)d_ws;
  unsigned short* assign = (unsigned short*)ws;               // [B][K][N] bf16, 4 MB
  float* vlad = (float*)(ws + 4194304);                       // [B][D][K] fp32, 4 MB
  unsigned short* xbf = (unsigned short*)(ws + 8388608);      // [B][D][N] bf16, 32 MB
  unsigned short* wbf = (unsigned short*)(ws + 41943040);     // [K][D] bf16, 64 KB
  float* asum = (float*)(ws + 42008576);                      // B*K
  float* colsq = asum + Bv * Kv;                              // B*K (contiguous)

  hipMemsetAsync(asum, 0, (size_t)2 * Bv * Kv * sizeof(float), stream);

  wconv<<<32, 256, 0, stream>>>(w, wbf);
  fused_scores<<<dim3(Nv / 64, Bv), 512, 0, stream>>>(x, wbf, xbf, assign, asum);
  vlad_mfma<<<dim3(Dv / 16, Bv), 512, 0, stream>>>(xbf, assign, centers, asum, vlad, colsq);
  scale_kernel<<<(Bv * Dv * Kv) / 256, 256, 0, stream>>>(vlad, colsq, out);
}